// Round 8
// baseline (31.511 us; speedup 1.0000x reference)
//
#include <hip/hip_runtime.h>

typedef unsigned long long u64;
typedef unsigned int u32;

#define NB 64      // graphs
#define NN 128     // nodes per graph
#define NITER 5
#define NGEN 6     // initial labels + 5 WL iterations
#define SALT 0xD1B54A32D192ED03ULL
#define NPAIR_OFF (NB*(NB-1)/2)  // 2016 strict lower-triangular pairs
#define TSLOTS 256

__device__ __forceinline__ u64 mix64(u64 x) {
    u64 z = x + 0x9E3779B97F4A7C15ULL;
    z = (z ^ (z >> 30)) * 0xBF58476D1CE4E5B9ULL;
    z = (z ^ (z >> 27)) * 0x94D049BB133111EBULL;
    return z ^ (z >> 31);
}

// K1: per-graph WL chain + hash-table build + Kdiag, one block per graph.
// 512 threads: pack phase uses all (4 quarter-masks per node via float4
// loads); WL phase runs on t<128 with the full 128-bit row mask in two
// u64 registers, ping-pong gsh -> ONE barrier per iteration; table build +
// export uses all 512 threads. Everything for one graph stays in-block.
__global__ __launch_bounds__(512) void wl_build(const float* __restrict__ adj,
                                                const int* __restrict__ labels,
                                                u64* __restrict__ hgen,
                                                u64* __restrict__ keysg,
                                                u32* __restrict__ cntsg,
                                                float* __restrict__ Kdiag,
                                                float* __restrict__ out) {
    const int b = blockIdx.x;
    const int t = threadIdx.x;
    const int u = t & 127;   // node
    const int q = t >> 7;    // quarter 0..3

    __shared__ u32 bits[4][NN];        // 2 KiB  quarter masks
    __shared__ u64 gsh[2][NN];         // 2 KiB  ping-pong neighbor feed
    __shared__ u64 hall[NGEN][NN];     // 6 KiB  all 6 generations
    __shared__ u64 keys[NGEN*TSLOTS];  // 12 KiB
    __shared__ u32 cnts[NGEN*TSLOTS];  // 6 KiB
    __shared__ u32 part[8];

    // ---- pack: thread (u,q) builds 32-bit mask of row u, cols 32q.. ----
    {
        const float* rowp = adj + ((size_t)b * NN + u) * NN + q * 32;
        u32 m = 0;
        #pragma unroll
        for (int k = 0; k < 8; ++k) {
            const float4 v = *(const float4*)(rowp + 4 * k);
            m |= (v.x > 0.5f ? 1u : 0u) << (4 * k);
            m |= (v.y > 0.5f ? 1u : 0u) << (4 * k + 1);
            m |= (v.z > 0.5f ? 1u : 0u) << (4 * k + 2);
            m |= (v.w > 0.5f ? 1u : 0u) << (4 * k + 3);
        }
        bits[q][u] = m;
    }
    // ---- zero tables: 1536 slots / 512 threads = 3 each ----
    #pragma unroll
    for (int k = 0; k < 3; ++k) { keys[t + 512 * k] = 0ULL; cnts[t + 512 * k] = 0u; }
    __syncthreads();

    // ---- WL chain: t<128 active, full mask in registers, 1 barrier/iter ----
    u64 h = 0, mA = 0, mB = 0;
    if (t < NN) {
        mA = (u64)bits[0][u] | ((u64)bits[1][u] << 32);
        mB = (u64)bits[2][u] | ((u64)bits[3][u] << 32);
        h = mix64((u64)(u32)labels[b * NN + u]);
        hall[0][u] = h;
        hgen[(size_t)b * (NGEN * NN) + u] = h;
    }
    for (int it = 0; it < NITER; ++it) {
        if (t < NN) gsh[it & 1][u] = mix64(h ^ SALT);
        __syncthreads();   // ping-pong buffer -> single barrier is sufficient
        if (t < NN) {
            const u64* gp = gsh[it & 1];
            u64 s = 0;
            u64 mm = mA;
            while (mm) { int j = __builtin_ctzll(mm); mm &= mm - 1; s += gp[j]; }
            mm = mB;
            while (mm) { int j = __builtin_ctzll(mm); mm &= mm - 1; s += gp[64 + j]; }
            h = mix64(mix64(h) + s);
            hall[it + 1][u] = h;
            hgen[(size_t)b * (NGEN * NN) + (it + 1) * NN + u] = h;
        }
    }
    __syncthreads();

    // ---- hash tables: 768 inserts over 512 threads (1-2 each) ----
    {
        const u64 key = hall[t >> 7][u];          // gens 0..3
        u32 s = ((u32)key & (TSLOTS - 1)) + (t >> 7) * TSLOTS;
        const u32 base = (t >> 7) * TSLOTS;
        for (;;) {
            u64 old = atomicCAS((unsigned long long*)&keys[s], 0ULL, key);
            if (old == 0ULL || old == key) { atomicAdd(&cnts[s], 1u); break; }
            s = base + ((s + 1) & (TSLOTS - 1));
        }
    }
    if (t < 256) {
        const int gen = 4 + (t >> 7);             // gens 4,5
        const u64 key = hall[gen][u];
        const u32 base = gen * TSLOTS;
        u32 s = ((u32)key & (TSLOTS - 1)) + base;
        for (;;) {
            u64 old = atomicCAS((unsigned long long*)&keys[s], 0ULL, key);
            if (old == 0ULL || old == key) { atomicAdd(&cnts[s], 1u); break; }
            s = base + ((s + 1) & (TSLOTS - 1));
        }
    }
    __syncthreads();

    // ---- export SoA + Kdiag = sum cnt^2 ----
    u32 acc = 0;
    #pragma unroll
    for (int k = 0; k < 3; ++k) {
        const int idx = t + 512 * k;
        const u64 kk = keys[idx];
        const u32 cc = cnts[idx];
        keysg[(size_t)b * (NGEN * TSLOTS) + idx] = kk;
        cntsg[(size_t)b * (NGEN * TSLOTS) + idx] = cc;
        acc += cc * cc;
    }
    #pragma unroll
    for (int off = 32; off > 0; off >>= 1) acc += __shfl_down(acc, off);
    if ((t & 63) == 0) part[t >> 6] = acc;
    __syncthreads();
    if (t == 0) {
        u32 d = 0;
        #pragma unroll
        for (int w = 0; w < 8; ++w) d += part[w];
        Kdiag[b] = sqrtf((float)d);
        out[b * NB + b] = 1.0f;
    }
}

// K2: one block per strict lower pair (b1>b2), 256 threads.
// Stage b2's 6 tables (SoA, 18 KiB), probe with b1's 768 labels (3/thread,
// coalesced global reads), normalize, write both triangles.
__global__ __launch_bounds__(256) void wl_pairs(const u64* __restrict__ hgen,
                                                const u64* __restrict__ keysg,
                                                const u32* __restrict__ cntsg,
                                                const float* __restrict__ Kdiag,
                                                float* __restrict__ out) {
    const int p = blockIdx.x;
    int b1 = (int)((1.0f + sqrtf(1.0f + 8.0f * (float)p)) * 0.5f);
    while (b1 * (b1 - 1) / 2 > p) --b1;
    while ((b1 + 1) * b1 / 2 <= p) ++b1;
    const int b2 = p - b1 * (b1 - 1) / 2;

    const int t = threadIdx.x;
    __shared__ u64 keys[NGEN * TSLOTS];  // 12 KiB
    __shared__ u32 cnts[NGEN * TSLOTS];  // 6 KiB

    {   // keys: 768 x ulonglong2 over 256 threads
        const ulonglong2* src = (const ulonglong2*)(keysg + (size_t)b2 * NGEN * TSLOTS);
        ulonglong2* dst = (ulonglong2*)keys;
        #pragma unroll
        for (int k = 0; k < 3; ++k) dst[t + 256 * k] = src[t + 256 * k];
    }
    {   // counts: 384 x uint4 over 256 threads
        const uint4* src = (const uint4*)(cntsg + (size_t)b2 * NGEN * TSLOTS);
        uint4* dst = (uint4*)cnts;
        #pragma unroll
        for (int k = 0; k < 2; ++k) {
            const int idx = t + 256 * k;
            if (idx < 384) dst[idx] = src[idx];
        }
    }
    __syncthreads();

    u32 c = 0;
    const u64* abase = hgen + (size_t)b1 * NGEN * NN;
    #pragma unroll
    for (int k = 0; k < 3; ++k) {
        const int idx = t + 256 * k;        // 0..767 -> gen = idx>>7
        const u64 a = abase[idx];
        const int base = (idx >> 7) * TSLOTS;
        u32 s = (u32)a & (TSLOTS - 1);
        for (;;) {
            const u64 kk = keys[base + s];
            if (kk == a) { c += cnts[base + s]; break; }
            if (kk == 0ULL) break;
            s = (s + 1) & (TSLOTS - 1);
        }
    }

    #pragma unroll
    for (int off = 32; off > 0; off >>= 1) c += __shfl_down(c, off);
    __shared__ u32 part[4];
    if ((t & 63) == 0) part[t >> 6] = c;
    __syncthreads();
    if (t == 0) {
        const float v = (float)(part[0] + part[1] + part[2] + part[3])
                      / (Kdiag[b1] * Kdiag[b2]);
        out[b1 * NB + b2] = v;
        out[b2 * NB + b1] = v;
    }
}

extern "C" void kernel_launch(void* const* d_in, const int* in_sizes, int n_in,
                              void* d_out, int out_size, void* d_ws, size_t ws_size,
                              hipStream_t stream) {
    const float* adj   = (const float*)d_in[0];   // [64,128,128] fp32 (0/1)
    const int*  labels = (const int*)d_in[1];     // [64,128] int32
    float* out = (float*)d_out;                   // [64,64] fp32

    char* ws = (char*)d_ws;
    u64*   hgen  = (u64*)ws;                       // 64*768*8  = 384 KiB
    u64*   keysg = (u64*)(ws + 512 * 1024);        // 64*1536*8 = 768 KiB
    u32*   cntsg = (u32*)(ws + 1536 * 1024);       // 64*1536*4 = 384 KiB
    float* Kdiag = (float*)(ws + 2048 * 1024);     // 256 B

    wl_build<<<NB, 512, 0, stream>>>(adj, labels, hgen, keysg, cntsg, Kdiag, out);
    wl_pairs<<<NPAIR_OFF, 256, 0, stream>>>(hgen, keysg, cntsg, Kdiag, out);
}